// Round 3
// baseline (3581.323 us; speedup 1.0000x reference)
//
#include <hip/hip_runtime.h>

// EGNN dynamics (alanine dipeptide), fp32, fully fused: one block per batch
// element, entire 4-layer message-passing loop in LDS/registers.
// R1: per-node precompute of the h_r/h_c halves of edge-GEMV1 (42x reuse).
// R2: conflict-minimizing edge enumeration (r = e%22 -> <=3-way LDS atomic
//     serialization instead of 21-way; rows/cols inputs no longer read) and
//     4-way partial accumulators in the W2 dot (break 64-deep FMA chain).

#define NPART   22
#define NDIM    3
#define XDIM    (NPART * NDIM)          // 66
#define H_IN    8
#define HID     64
#define NLAYERS 4
#define EPB     (NPART * (NPART - 1))   // 462 edges per batch
#define BLOCK   256

__device__ __forceinline__ float silu_f(float x) {
    // x * sigmoid(x) = x / (1 + exp(-x)); fast HW exp + fast reciprocal.
    return __fdividef(x, 1.0f + __expf(-x));
}

// acc[0..63] += e0 * w_row[0..63]   (row is 64 contiguous floats, wave-uniform)
#define ACC16(ARR, WPTR, E0) do {                                   \
    const float4* _w4 = (const float4*)(WPTR);                      \
    _Pragma("unroll")                                               \
    for (int _q = 0; _q < 16; ++_q) {                               \
        float4 _w = _w4[_q];                                        \
        ARR[4*_q+0] = fmaf((E0), _w.x, ARR[4*_q+0]);                \
        ARR[4*_q+1] = fmaf((E0), _w.y, ARR[4*_q+1]);                \
        ARR[4*_q+2] = fmaf((E0), _w.z, ARR[4*_q+2]);                \
        ARR[4*_q+3] = fmaf((E0), _w.w, ARR[4*_q+3]);                \
    }                                                               \
} while (0)

// acc[0..7] += e0 * w[0..7]
#define ACC8(ARR, WPTR, E0) do {                                    \
    const float4* _w4 = (const float4*)(WPTR);                      \
    float4 _wa = _w4[0], _wb = _w4[1];                              \
    ARR[0] = fmaf((E0), _wa.x, ARR[0]);                             \
    ARR[1] = fmaf((E0), _wa.y, ARR[1]);                             \
    ARR[2] = fmaf((E0), _wa.z, ARR[2]);                             \
    ARR[3] = fmaf((E0), _wa.w, ARR[3]);                             \
    ARR[4] = fmaf((E0), _wb.x, ARR[4]);                             \
    ARR[5] = fmaf((E0), _wb.y, ARR[5]);                             \
    ARR[6] = fmaf((E0), _wb.z, ARR[6]);                             \
    ARR[7] = fmaf((E0), _wb.w, ARR[7]);                             \
} while (0)

#define LOAD64(ARR, PTR) do {                                       \
    const float4* _b4 = (const float4*)(PTR);                       \
    _Pragma("unroll")                                               \
    for (int _q = 0; _q < 16; ++_q) {                               \
        float4 _w = _b4[_q];                                        \
        ARR[4*_q+0] = _w.x; ARR[4*_q+1] = _w.y;                     \
        ARR[4*_q+2] = _w.z; ARR[4*_q+3] = _w.w;                     \
    }                                                               \
} while (0)

__global__ void __launch_bounds__(BLOCK)
w2_transpose_kernel(const float* __restrict__ w2, float* __restrict__ w2t) {
    int l = blockIdx.x;
    for (int i = threadIdx.x; i < HID * HID; i += BLOCK) {
        int k = i >> 6, j = i & 63;
        w2t[l * HID * HID + j * HID + k] = w2[l * HID * HID + k * HID + j];
    }
}

// Edge enumeration: e in [0, 462), r = e % 22, c = (r + 1 + e/22) % 22.
// Covers all ordered pairs r != c; within a 64-lane wave each r appears <= 3
// times -> LDS atomic serialization <= 3-way (reference ordering was 21-way).
__device__ __forceinline__ void edge_rc(int e, int& r, int& c) {
    int k = e / NPART;            // 0..20
    r = e - k * NPART;            // e % 22
    c = r + 1 + k;
    if (c >= NPART) c -= NPART;
}

template <bool TRANSPOSED>
__global__ void __launch_bounds__(BLOCK)
egnn_fused_kernel(const float* __restrict__ t_in,
                  const float* __restrict__ xs,
                  const float* __restrict__ h_init,
                  const float* __restrict__ emb_w,
                  const float* __restrict__ emb_b,
                  const float* __restrict__ edge_w1,
                  const float* __restrict__ edge_b1,
                  const float* __restrict__ edge_w2x,  // transposed (d_ws) or raw
                  const float* __restrict__ edge_b2,
                  const float* __restrict__ node_w1,
                  const float* __restrict__ node_b1,
                  const float* __restrict__ node_w2,
                  const float* __restrict__ node_b2,
                  const float* __restrict__ coord_w1,
                  const float* __restrict__ coord_b1,
                  const float* __restrict__ coord_w2,
                  float*       __restrict__ out) {
    // LDS state, [feature][node] layout (stride NPART=22 -> bank-conflict-free
    // gathers: distinct nodes < 32 hit distinct banks, duplicates broadcast).
    __shared__ float h_s   [HID * NPART];
    __shared__ float hagg_s[HID * NPART];
    __shared__ float ns_s  [HID * NPART];
    __shared__ float pr_s  [HID * NPART];   // b1 + h @ W1[0:64]   per node
    __shared__ float pc_s  [HID * NPART];   //      h @ W1[64:128] per node
    __shared__ float x_s[XDIM], x0_s[XDIM], xacc_s[XDIM];
    __shared__ float ea_s[EPB];
    __shared__ float mean_s[NDIM];

    const int b   = blockIdx.x;
    const int tid = threadIdx.x;
    const float tval = t_in[b];

    // ---- setup: coords, h embedding ----
    if (tid < XDIM) {
        float v = xs[b * XDIM + tid];
        x0_s[tid] = v;
        x_s[tid]  = v;
    }
    for (int idx = tid; idx < NPART * HID; idx += BLOCK) {
        int n = idx >> 6, j = idx & 63;
        float acc = emb_b[j] + tval * emb_w[H_IN * HID + j];
#pragma unroll
        for (int k = 0; k < H_IN; ++k)
            acc = fmaf(h_init[n * H_IN + k], emb_w[k * HID + j], acc);
        h_s[j * NPART + n] = acc;   // no activation on embedding
    }
    __syncthreads();
    // static edge attribute: squared distance at x0
    for (int e = tid; e < EPB; e += BLOCK) {
        int r, c; edge_rc(e, r, c);
        float dx = x0_s[r*3+0] - x0_s[c*3+0];
        float dy = x0_s[r*3+1] - x0_s[c*3+1];
        float dz = x0_s[r*3+2] - x0_s[c*3+2];
        ea_s[e] = dx*dx + dy*dy + dz*dz;
    }
    __syncthreads();

    for (int l = 0; l < NLAYERS; ++l) {
        const float* ew1 = edge_w1  + l * (2*HID + 2) * HID;
        const float* eb1 = edge_b1  + l * HID;
        const float* w2x = edge_w2x + l * HID * HID;
        const float* eb2 = edge_b2  + l * HID;
        const float* cw1 = coord_w1 + l * HID * HID;
        const float* cb1 = coord_b1 + l * HID;
        const float* cw2 = coord_w2 + l * HID;
        const float* nw1 = node_w1  + l * 2 * HID * HID;
        const float* nb1 = node_b1  + l * HID;
        const float* nw2 = node_w2  + l * HID * HID;
        const float* nb2 = node_b2  + l * HID;

        // zero aggregators
        for (int idx = tid; idx < NPART * HID; idx += BLOCK) hagg_s[idx] = 0.0f;
        if (tid < XDIM) xacc_s[tid] = 0.0f;

        // ---- per-node precompute of edge-GEMV1 halves (176 threads) ----
        // pr[n][j] = eb1[j] + sum_k h[n][k] * W1[k][j]
        // pc[n][j] =          sum_k h[n][k] * W1[64+k][j]
        if (tid < NPART * 8) {
            int n = tid >> 3, jg = tid & 7;
            float pr[8], pc[8];
            {
                const float4* b4 = (const float4*)(eb1 + jg * 8);
                float4 wa = b4[0], wb = b4[1];
                pr[0]=wa.x; pr[1]=wa.y; pr[2]=wa.z; pr[3]=wa.w;
                pr[4]=wb.x; pr[5]=wb.y; pr[6]=wb.z; pr[7]=wb.w;
            }
#pragma unroll
            for (int jj = 0; jj < 8; ++jj) pc[jj] = 0.0f;
            for (int k = 0; k < HID; ++k) {
                float e0 = h_s[k * NPART + n];
                ACC8(pr, ew1 + k * HID + jg * 8, e0);
                ACC8(pc, ew1 + (HID + k) * HID + jg * 8, e0);
            }
#pragma unroll
            for (int jj = 0; jj < 8; ++jj) {
                pr_s[(jg * 8 + jj) * NPART + n] = pr[jj];
                pc_s[(jg * 8 + jj) * NPART + n] = pc[jj];
            }
        }
        __syncthreads();

        // ---- edge phase: one thread per edge ----
        for (int e = tid; e < EPB; e += BLOCK) {
            int r, c; edge_rc(e, r, c);
            float dx = x_s[r*3+0] - x_s[c*3+0];
            float dy = x_s[r*3+1] - x_s[c*3+1];
            float dz = x_s[r*3+2] - x_s[c*3+2];
            float radial = dx*dx + dy*dy + dz*dz;
            float invn = __fdividef(1.0f, sqrtf(radial) + 1.0f);
            float ux = dx * invn, uy = dy * invn, uz = dz * invn;
            float ea = ea_s[e];

            // a = silu(P_r[r] + P_c[c] + radial*W1[128,:] + ea*W1[129,:])
            float a[HID];
#pragma unroll
            for (int j = 0; j < HID; ++j) {
                float v = pr_s[j * NPART + r] + pc_s[j * NPART + c];
                v = fmaf(radial, ew1[(2 * HID) * HID + j], v);
                v = fmaf(ea,     ew1[(2 * HID + 1) * HID + j], v);
                a[j] = silu_f(v);
            }

            // fused: m_j = silu(a @ W2 + b2)_j, immediately consumed by
            //   (1) hagg LDS-atomic, (2) coord-MLP hidden accumulation t1.
            float t1[HID];
            LOAD64(t1, cb1);
#pragma unroll
            for (int j = 0; j < HID; ++j) {
                // 4 partial sums -> FMA chain depth 16 instead of 64.
                float m0, m1, m2, m3;
                if constexpr (TRANSPOSED) {
                    const float4* w4 = (const float4*)(w2x + j * HID);
                    m0 = eb2[j]; m1 = 0.0f; m2 = 0.0f; m3 = 0.0f;
#pragma unroll
                    for (int q = 0; q < 4; ++q) {
                        float4 wA = w4[4*q+0], wB = w4[4*q+1];
                        float4 wC = w4[4*q+2], wD = w4[4*q+3];
                        m0 = fmaf(a[16*q+ 0], wA.x, m0);
                        m0 = fmaf(a[16*q+ 1], wA.y, m0);
                        m0 = fmaf(a[16*q+ 2], wA.z, m0);
                        m0 = fmaf(a[16*q+ 3], wA.w, m0);
                        m1 = fmaf(a[16*q+ 4], wB.x, m1);
                        m1 = fmaf(a[16*q+ 5], wB.y, m1);
                        m1 = fmaf(a[16*q+ 6], wB.z, m1);
                        m1 = fmaf(a[16*q+ 7], wB.w, m1);
                        m2 = fmaf(a[16*q+ 8], wC.x, m2);
                        m2 = fmaf(a[16*q+ 9], wC.y, m2);
                        m2 = fmaf(a[16*q+10], wC.z, m2);
                        m2 = fmaf(a[16*q+11], wC.w, m2);
                        m3 = fmaf(a[16*q+12], wD.x, m3);
                        m3 = fmaf(a[16*q+13], wD.y, m3);
                        m3 = fmaf(a[16*q+14], wD.z, m3);
                        m3 = fmaf(a[16*q+15], wD.w, m3);
                    }
                } else {
                    m0 = eb2[j]; m1 = 0.0f; m2 = 0.0f; m3 = 0.0f;
#pragma unroll
                    for (int k = 0; k < HID; k += 4) {
                        m0 = fmaf(a[k+0], w2x[(k+0) * HID + j], m0);
                        m1 = fmaf(a[k+1], w2x[(k+1) * HID + j], m1);
                        m2 = fmaf(a[k+2], w2x[(k+2) * HID + j], m2);
                        m3 = fmaf(a[k+3], w2x[(k+3) * HID + j], m3);
                    }
                }
                float mj = silu_f((m0 + m1) + (m2 + m3));
                atomicAdd(&hagg_s[j * NPART + r], mj);
                ACC16(t1, cw1 + j * HID, mj);   // t1 += m_j * CW1[j,:]
            }
#pragma unroll
            for (int q = 0; q < HID; ++q) t1[q] = silu_f(t1[q]);

            float phi = 0.0f;
            {
                const float4* w4 = (const float4*)cw2;
#pragma unroll
                for (int q = 0; q < 16; ++q) {
                    float4 w = w4[q];
                    phi = fmaf(t1[4*q+0], w.x, phi);
                    phi = fmaf(t1[4*q+1], w.y, phi);
                    phi = fmaf(t1[4*q+2], w.z, phi);
                    phi = fmaf(t1[4*q+3], w.w, phi);
                }
            }
            atomicAdd(&xacc_s[r*3+0], ux * phi);
            atomicAdd(&xacc_s[r*3+1], uy * phi);
            atomicAdd(&xacc_s[r*3+2], uz * phi);
        }
        __syncthreads();

        // ---- node phase: 176 threads = 22 nodes x 8 column-groups ----
        if (tid < NPART * 8) {
            int n = tid >> 3, jg = tid & 7;
            float acc[8];
            {
                const float4* b4 = (const float4*)(nb1 + jg * 8);
                float4 wa = b4[0], wb = b4[1];
                acc[0]=wa.x; acc[1]=wa.y; acc[2]=wa.z; acc[3]=wa.w;
                acc[4]=wb.x; acc[5]=wb.y; acc[6]=wb.z; acc[7]=wb.w;
            }
            for (int k = 0; k < HID; ++k) {
                float e0 = h_s[k * NPART + n];
                ACC8(acc, nw1 + k * HID + jg * 8, e0);
            }
            for (int k = 0; k < HID; ++k) {
                float e0 = hagg_s[k * NPART + n];
                ACC8(acc, nw1 + (HID + k) * HID + jg * 8, e0);
            }
#pragma unroll
            for (int jj = 0; jj < 8; ++jj)
                ns_s[(jg * 8 + jj) * NPART + n] = silu_f(acc[jj]);
        }
        __syncthreads();
        if (tid < NPART * 8) {
            int n = tid >> 3, jg = tid & 7;
            float acc[8];
            {
                const float4* b4 = (const float4*)(nb2 + jg * 8);
                float4 wa = b4[0], wb = b4[1];
                acc[0]=wa.x; acc[1]=wa.y; acc[2]=wa.z; acc[3]=wa.w;
                acc[4]=wb.x; acc[5]=wb.y; acc[6]=wb.z; acc[7]=wb.w;
            }
            for (int k = 0; k < HID; ++k) {
                float e0 = ns_s[k * NPART + n];
                ACC8(acc, nw2 + k * HID + jg * 8, e0);
            }
#pragma unroll
            for (int jj = 0; jj < 8; ++jj)
                h_s[(jg * 8 + jj) * NPART + n] += acc[jj];   // residual
        } else if (tid >= NPART * 8 && tid < NPART * 8 + XDIM) {
            int i = tid - NPART * 8;
            x_s[i] += xacc_s[i];                             // coord residual
        }
        __syncthreads();
    }

    // ---- output: vel = (x - x0) minus per-batch mean over particles ----
    if (tid < XDIM) xacc_s[tid] = x_s[tid] - x0_s[tid];
    __syncthreads();
    if (tid < NDIM) {
        float s = 0.0f;
#pragma unroll
        for (int n = 0; n < NPART; ++n) s += xacc_s[n * NDIM + tid];
        mean_s[tid] = s * (1.0f / NPART);
    }
    __syncthreads();
    if (tid < XDIM) {
        int d = tid - (tid / 3) * 3;
        out[b * XDIM + tid] = xacc_s[tid] - mean_s[d];
    }
}

extern "C" void kernel_launch(void* const* d_in, const int* in_sizes, int n_in,
                              void* d_out, int out_size, void* d_ws, size_t ws_size,
                              hipStream_t stream) {
    const float* t_in    = (const float*)d_in[0];
    const float* xs      = (const float*)d_in[1];
    const float* h_init  = (const float*)d_in[2];
    const float* emb_w   = (const float*)d_in[3];
    const float* emb_b   = (const float*)d_in[4];
    const float* edge_w1 = (const float*)d_in[5];
    const float* edge_b1 = (const float*)d_in[6];
    const float* edge_w2 = (const float*)d_in[7];
    const float* edge_b2 = (const float*)d_in[8];
    const float* node_w1 = (const float*)d_in[9];
    const float* node_b1 = (const float*)d_in[10];
    const float* node_w2 = (const float*)d_in[11];
    const float* node_b2 = (const float*)d_in[12];
    const float* coord_w1= (const float*)d_in[13];
    const float* coord_b1= (const float*)d_in[14];
    const float* coord_w2= (const float*)d_in[15];
    float* out = (float*)d_out;

    const int B = in_sizes[0];                 // 1024
    const size_t w2t_bytes = (size_t)NLAYERS * HID * HID * sizeof(float);

    if (ws_size >= w2t_bytes) {
        float* w2t = (float*)d_ws;
        hipLaunchKernelGGL(w2_transpose_kernel, dim3(NLAYERS), dim3(BLOCK), 0,
                           stream, edge_w2, w2t);
        hipLaunchKernelGGL((egnn_fused_kernel<true>), dim3(B), dim3(BLOCK), 0,
                           stream, t_in, xs, h_init, emb_w, emb_b,
                           edge_w1, edge_b1, w2t, edge_b2,
                           node_w1, node_b1, node_w2, node_b2,
                           coord_w1, coord_b1, coord_w2, out);
    } else {
        hipLaunchKernelGGL((egnn_fused_kernel<false>), dim3(B), dim3(BLOCK), 0,
                           stream, t_in, xs, h_init, emb_w, emb_b,
                           edge_w1, edge_b1, edge_w2, edge_b2,
                           node_w1, node_b1, node_w2, node_b2,
                           coord_w1, coord_b1, coord_w2, out);
    }
}

// Round 7
// 2711.656 us; speedup vs baseline: 1.3207x; 1.3207x over previous
//
#include <hip/hip_runtime.h>

// EGNN dynamics (alanine dipeptide), fp32, fully fused: one block per batch
// element, entire 4-layer message-passing loop in LDS/registers.
// R1: per-node precompute of the h_r/h_c halves of edge-GEMV1 (42x reuse).
// R2: conflict-minimizing edge enumeration + 4-way partial accumulators.
//     BENCH: VGPR=256 cap, 122MB spill writes/dispatch, occupancy 12%,
//     VALUBusy 37%, 3581us -> register-pressure bound, not FLOP bound.
// R3 (unbenched): partial unroll on a[j]/t1[q] loops -> runtime indices ->
//     SROA fails -> arrays in scratch (rule #20). Withdrawn.
// R4 (unbenched): full unroll on ALL register-array loops; m-loop unroll 2;
//     weight vectors staged in LDS.
// R5 (unbenched): audit fixes on R4: (a) wc_s staging hole (WC_N=320 >
//     BLOCK=256) -> strided loop; (b) pin edge loop (trip 2) and layer loop
//     at unroll 1 so the compiler can't re-double live ranges.
// R6: R5 resubmitted verbatim after a second full audit (no defects found;
//     GPU never acquired for R3-R5). No new deltas — next bench must give a
//     clean signal on the R4/R5 anti-spill design.

#define NPART   22
#define NDIM    3
#define XDIM    (NPART * NDIM)          // 66
#define H_IN    8
#define HID     64
#define NLAYERS 4
#define EPB     (NPART * (NPART - 1))   // 462 edges per batch
#define BLOCK   256

__device__ __forceinline__ float silu_f(float x) {
    // x * sigmoid(x) = x / (1 + exp(-x)); fast HW exp + fast reciprocal.
    return __fdividef(x, 1.0f + __expf(-x));
}

// acc[0..63] += e0 * w_row[0..63]   (row is 64 contiguous floats, wave-uniform)
#define ACC16(ARR, WPTR, E0) do {                                   \
    const float4* _w4 = (const float4*)(WPTR);                      \
    _Pragma("unroll")                                               \
    for (int _q = 0; _q < 16; ++_q) {                               \
        float4 _w = _w4[_q];                                        \
        ARR[4*_q+0] = fmaf((E0), _w.x, ARR[4*_q+0]);                \
        ARR[4*_q+1] = fmaf((E0), _w.y, ARR[4*_q+1]);                \
        ARR[4*_q+2] = fmaf((E0), _w.z, ARR[4*_q+2]);                \
        ARR[4*_q+3] = fmaf((E0), _w.w, ARR[4*_q+3]);                \
    }                                                               \
} while (0)

// acc[0..7] += e0 * w[0..7]
#define ACC8(ARR, WPTR, E0) do {                                    \
    const float4* _w4 = (const float4*)(WPTR);                      \
    float4 _wa = _w4[0], _wb = _w4[1];                              \
    ARR[0] = fmaf((E0), _wa.x, ARR[0]);                             \
    ARR[1] = fmaf((E0), _wa.y, ARR[1]);                             \
    ARR[2] = fmaf((E0), _wa.z, ARR[2]);                             \
    ARR[3] = fmaf((E0), _wa.w, ARR[3]);                             \
    ARR[4] = fmaf((E0), _wb.x, ARR[4]);                             \
    ARR[5] = fmaf((E0), _wb.y, ARR[5]);                             \
    ARR[6] = fmaf((E0), _wb.z, ARR[6]);                             \
    ARR[7] = fmaf((E0), _wb.w, ARR[7]);                             \
} while (0)

__global__ void __launch_bounds__(BLOCK)
w2_transpose_kernel(const float* __restrict__ w2, float* __restrict__ w2t) {
    int l = blockIdx.x;
    for (int i = threadIdx.x; i < HID * HID; i += BLOCK) {
        int k = i >> 6, j = i & 63;
        w2t[l * HID * HID + j * HID + k] = w2[l * HID * HID + k * HID + j];
    }
}

// Edge enumeration: e in [0, 462), r = e % 22, c = (r + 1 + e/22) % 22.
// Covers all ordered pairs r != c; within a 64-lane wave each r appears <= 3
// times -> LDS atomic serialization <= 3-way (reference ordering was 21-way).
__device__ __forceinline__ void edge_rc(int e, int& r, int& c) {
    int k = e / NPART;            // 0..20
    r = e - k * NPART;            // e % 22
    c = r + 1 + k;
    if (c >= NPART) c -= NPART;
}

// per-layer LDS weight-vector cache offsets
#define WC_RW   0      // W1 row 128 (radial)
#define WC_EA   64     // W1 row 129 (edge_attr)
#define WC_EB2  128    // edge_b2
#define WC_CB1  192    // coord_b1
#define WC_CW2  256    // coord_w2
#define WC_N    320

template <bool TRANSPOSED>
__global__ void __launch_bounds__(BLOCK)
egnn_fused_kernel(const float* __restrict__ t_in,
                  const float* __restrict__ xs,
                  const float* __restrict__ h_init,
                  const float* __restrict__ emb_w,
                  const float* __restrict__ emb_b,
                  const float* __restrict__ edge_w1,
                  const float* __restrict__ edge_b1,
                  const float* __restrict__ edge_w2x,  // transposed (d_ws) or raw
                  const float* __restrict__ edge_b2,
                  const float* __restrict__ node_w1,
                  const float* __restrict__ node_b1,
                  const float* __restrict__ node_w2,
                  const float* __restrict__ node_b2,
                  const float* __restrict__ coord_w1,
                  const float* __restrict__ coord_b1,
                  const float* __restrict__ coord_w2,
                  float*       __restrict__ out) {
    // LDS state, [feature][node] layout (stride NPART=22 -> bank-conflict-free
    // gathers: distinct nodes < 32 hit distinct banks, duplicates broadcast).
    __shared__ float h_s   [HID * NPART];
    __shared__ float hagg_s[HID * NPART];
    __shared__ float ns_s  [HID * NPART];
    __shared__ float pr_s  [HID * NPART];   // b1 + h @ W1[0:64]   per node
    __shared__ float pc_s  [HID * NPART];   //      h @ W1[64:128] per node
    __shared__ float wc_s  [WC_N];          // per-layer weight vectors
    __shared__ float x_s[XDIM], x0_s[XDIM], xacc_s[XDIM];
    __shared__ float ea_s[EPB];
    __shared__ float mean_s[NDIM];

    const int b   = blockIdx.x;
    const int tid = threadIdx.x;
    const float tval = t_in[b];

    // ---- setup: coords, h embedding ----
    if (tid < XDIM) {
        float v = xs[b * XDIM + tid];
        x0_s[tid] = v;
        x_s[tid]  = v;
    }
    for (int idx = tid; idx < NPART * HID; idx += BLOCK) {
        int n = idx >> 6, j = idx & 63;
        float acc = emb_b[j] + tval * emb_w[H_IN * HID + j];
#pragma unroll
        for (int k = 0; k < H_IN; ++k)
            acc = fmaf(h_init[n * H_IN + k], emb_w[k * HID + j], acc);
        h_s[j * NPART + n] = acc;   // no activation on embedding
    }
    __syncthreads();
    // static edge attribute: squared distance at x0
    for (int e = tid; e < EPB; e += BLOCK) {
        int r, c; edge_rc(e, r, c);
        float dx = x0_s[r*3+0] - x0_s[c*3+0];
        float dy = x0_s[r*3+1] - x0_s[c*3+1];
        float dz = x0_s[r*3+2] - x0_s[c*3+2];
        ea_s[e] = dx*dx + dy*dy + dz*dz;
    }
    __syncthreads();

#pragma unroll 1
    for (int l = 0; l < NLAYERS; ++l) {
        const float* ew1 = edge_w1  + l * (2*HID + 2) * HID;
        const float* eb1 = edge_b1  + l * HID;
        const float* w2x = edge_w2x + l * HID * HID;
        const float* eb2 = edge_b2  + l * HID;
        const float* cw1 = coord_w1 + l * HID * HID;
        const float* cb1 = coord_b1 + l * HID;
        const float* cw2 = coord_w2 + l * HID;
        const float* nw1 = node_w1  + l * 2 * HID * HID;
        const float* nb1 = node_b1  + l * HID;
        const float* nw2 = node_w2  + l * HID * HID;
        const float* nb2 = node_b2  + l * HID;

        // zero aggregators + stage per-layer weight vectors into LDS
        for (int idx = tid; idx < NPART * HID; idx += BLOCK) hagg_s[idx] = 0.0f;
        if (tid < XDIM) xacc_s[tid] = 0.0f;
        // strided: WC_N (320) > BLOCK (256).
        for (int idx = tid; idx < WC_N; idx += BLOCK) {
            int g = idx >> 6, j = idx & 63;
            float v;
            if      (g == 0) v = ew1[(2 * HID) * HID + j];
            else if (g == 1) v = ew1[(2 * HID + 1) * HID + j];
            else if (g == 2) v = eb2[j];
            else if (g == 3) v = cb1[j];
            else             v = cw2[j];
            wc_s[idx] = v;
        }

        // ---- per-node precompute of edge-GEMV1 halves (176 threads) ----
        // pr[n][j] = eb1[j] + sum_k h[n][k] * W1[k][j]
        // pc[n][j] =          sum_k h[n][k] * W1[64+k][j]
        if (tid < NPART * 8) {
            int n = tid >> 3, jg = tid & 7;
            float pr[8], pc[8];
            {
                const float4* b4 = (const float4*)(eb1 + jg * 8);
                float4 wa = b4[0], wb = b4[1];
                pr[0]=wa.x; pr[1]=wa.y; pr[2]=wa.z; pr[3]=wa.w;
                pr[4]=wb.x; pr[5]=wb.y; pr[6]=wb.z; pr[7]=wb.w;
            }
#pragma unroll
            for (int jj = 0; jj < 8; ++jj) pc[jj] = 0.0f;
#pragma unroll 1
            for (int k = 0; k < HID; ++k) {     // runtime k: pointers only
                float e0 = h_s[k * NPART + n];
                ACC8(pr, ew1 + k * HID + jg * 8, e0);
                ACC8(pc, ew1 + (HID + k) * HID + jg * 8, e0);
            }
#pragma unroll
            for (int jj = 0; jj < 8; ++jj) {
                pr_s[(jg * 8 + jj) * NPART + n] = pr[jj];
                pc_s[(jg * 8 + jj) * NPART + n] = pc[jj];
            }
        }
        __syncthreads();

        // ---- edge phase: one thread per edge ----
        // unroll 1: trip count is 2 — compiler x2 unroll would double the
        // a[]+t1[] live set and spill (R2 lesson).
#pragma unroll 1
        for (int e = tid; e < EPB; e += BLOCK) {
            int r, c; edge_rc(e, r, c);
            float dx = x_s[r*3+0] - x_s[c*3+0];
            float dy = x_s[r*3+1] - x_s[c*3+1];
            float dz = x_s[r*3+2] - x_s[c*3+2];
            float radial = dx*dx + dy*dy + dz*dz;
            float invn = __fdividef(1.0f, sqrtf(radial) + 1.0f);
            float ux = dx * invn, uy = dy * invn, uz = dz * invn;
            float ea = ea_s[e];

            // a = silu(P_r[r] + P_c[c] + radial*W1[128,:] + ea*W1[129,:])
            // FULL unroll: every a[] index compile-time (register residency).
            float a[HID];
#pragma unroll
            for (int j = 0; j < HID; ++j) {
                float v = pr_s[j * NPART + r] + pc_s[j * NPART + c];
                v = fmaf(radial, wc_s[WC_RW + j], v);
                v = fmaf(ea,     wc_s[WC_EA + j], v);
                a[j] = silu_f(v);
            }

            // t1 init from LDS-cached coord_b1 (broadcast reads)
            float t1[HID];
#pragma unroll
            for (int q = 0; q < 16; ++q) {
                float4 w = ((const float4*)(wc_s + WC_CB1))[q];
                t1[4*q+0] = w.x; t1[4*q+1] = w.y;
                t1[4*q+2] = w.z; t1[4*q+3] = w.w;
            }

            // fused: m_j = silu(a @ W2 + b2)_j, immediately consumed by
            //   (1) hagg LDS-atomic, (2) coord-MLP hidden accumulation t1.
            // unroll 2 (NOT full): inner indices already compile-time; caps
            // in-flight weight temps (R2's full unroll spilled at VGPR=256).
#pragma unroll 2
            for (int j = 0; j < HID; ++j) {
                // 4 partial sums -> FMA chain depth 16 instead of 64.
                float m0, m1, m2, m3;
                if constexpr (TRANSPOSED) {
                    const float4* w4 = (const float4*)(w2x + j * HID);
                    m0 = wc_s[WC_EB2 + j]; m1 = 0.0f; m2 = 0.0f; m3 = 0.0f;
#pragma unroll
                    for (int q = 0; q < 4; ++q) {
                        float4 wA = w4[4*q+0], wB = w4[4*q+1];
                        float4 wC = w4[4*q+2], wD = w4[4*q+3];
                        m0 = fmaf(a[16*q+ 0], wA.x, m0);
                        m0 = fmaf(a[16*q+ 1], wA.y, m0);
                        m0 = fmaf(a[16*q+ 2], wA.z, m0);
                        m0 = fmaf(a[16*q+ 3], wA.w, m0);
                        m1 = fmaf(a[16*q+ 4], wB.x, m1);
                        m1 = fmaf(a[16*q+ 5], wB.y, m1);
                        m1 = fmaf(a[16*q+ 6], wB.z, m1);
                        m1 = fmaf(a[16*q+ 7], wB.w, m1);
                        m2 = fmaf(a[16*q+ 8], wC.x, m2);
                        m2 = fmaf(a[16*q+ 9], wC.y, m2);
                        m2 = fmaf(a[16*q+10], wC.z, m2);
                        m2 = fmaf(a[16*q+11], wC.w, m2);
                        m3 = fmaf(a[16*q+12], wD.x, m3);
                        m3 = fmaf(a[16*q+13], wD.y, m3);
                        m3 = fmaf(a[16*q+14], wD.z, m3);
                        m3 = fmaf(a[16*q+15], wD.w, m3);
                    }
                } else {
                    m0 = wc_s[WC_EB2 + j]; m1 = 0.0f; m2 = 0.0f; m3 = 0.0f;
#pragma unroll
                    for (int k = 0; k < HID; k += 4) {
                        m0 = fmaf(a[k+0], w2x[(k+0) * HID + j], m0);
                        m1 = fmaf(a[k+1], w2x[(k+1) * HID + j], m1);
                        m2 = fmaf(a[k+2], w2x[(k+2) * HID + j], m2);
                        m3 = fmaf(a[k+3], w2x[(k+3) * HID + j], m3);
                    }
                }
                float mj = silu_f((m0 + m1) + (m2 + m3));
                atomicAdd(&hagg_s[j * NPART + r], mj);
                ACC16(t1, cw1 + j * HID, mj);   // t1 += m_j * CW1[j,:]
            }

            // phi = silu(t1) . cw2   (FULL unroll: t1[] indices compile-time)
            float phi = 0.0f;
#pragma unroll
            for (int q = 0; q < 16; ++q) {
                float4 w = ((const float4*)(wc_s + WC_CW2))[q];
                phi = fmaf(silu_f(t1[4*q+0]), w.x, phi);
                phi = fmaf(silu_f(t1[4*q+1]), w.y, phi);
                phi = fmaf(silu_f(t1[4*q+2]), w.z, phi);
                phi = fmaf(silu_f(t1[4*q+3]), w.w, phi);
            }
            atomicAdd(&xacc_s[r*3+0], ux * phi);
            atomicAdd(&xacc_s[r*3+1], uy * phi);
            atomicAdd(&xacc_s[r*3+2], uz * phi);
        }
        __syncthreads();

        // ---- node phase: 176 threads = 22 nodes x 8 column-groups ----
        if (tid < NPART * 8) {
            int n = tid >> 3, jg = tid & 7;
            float acc[8];
            {
                const float4* b4 = (const float4*)(nb1 + jg * 8);
                float4 wa = b4[0], wb = b4[1];
                acc[0]=wa.x; acc[1]=wa.y; acc[2]=wa.z; acc[3]=wa.w;
                acc[4]=wb.x; acc[5]=wb.y; acc[6]=wb.z; acc[7]=wb.w;
            }
#pragma unroll 1
            for (int k = 0; k < HID; ++k) {
                float e0 = h_s[k * NPART + n];
                ACC8(acc, nw1 + k * HID + jg * 8, e0);
            }
#pragma unroll 1
            for (int k = 0; k < HID; ++k) {
                float e0 = hagg_s[k * NPART + n];
                ACC8(acc, nw1 + (HID + k) * HID + jg * 8, e0);
            }
#pragma unroll
            for (int jj = 0; jj < 8; ++jj)
                ns_s[(jg * 8 + jj) * NPART + n] = silu_f(acc[jj]);
        }
        __syncthreads();
        if (tid < NPART * 8) {
            int n = tid >> 3, jg = tid & 7;
            float acc[8];
            {
                const float4* b4 = (const float4*)(nb2 + jg * 8);
                float4 wa = b4[0], wb = b4[1];
                acc[0]=wa.x; acc[1]=wa.y; acc[2]=wa.z; acc[3]=wa.w;
                acc[4]=wb.x; acc[5]=wb.y; acc[6]=wb.z; acc[7]=wb.w;
            }
#pragma unroll 1
            for (int k = 0; k < HID; ++k) {
                float e0 = ns_s[k * NPART + n];
                ACC8(acc, nw2 + k * HID + jg * 8, e0);
            }
#pragma unroll
            for (int jj = 0; jj < 8; ++jj)
                h_s[(jg * 8 + jj) * NPART + n] += acc[jj];   // residual
        } else if (tid >= NPART * 8 && tid < NPART * 8 + XDIM) {
            int i = tid - NPART * 8;
            x_s[i] += xacc_s[i];                             // coord residual
        }
        __syncthreads();
    }

    // ---- output: vel = (x - x0) minus per-batch mean over particles ----
    if (tid < XDIM) xacc_s[tid] = x_s[tid] - x0_s[tid];
    __syncthreads();
    if (tid < NDIM) {
        float s = 0.0f;
#pragma unroll
        for (int n = 0; n < NPART; ++n) s += xacc_s[n * NDIM + tid];
        mean_s[tid] = s * (1.0f / NPART);
    }
    __syncthreads();
    if (tid < XDIM) {
        int d = tid - (tid / 3) * 3;
        out[b * XDIM + tid] = xacc_s[tid] - mean_s[d];
    }
}

extern "C" void kernel_launch(void* const* d_in, const int* in_sizes, int n_in,
                              void* d_out, int out_size, void* d_ws, size_t ws_size,
                              hipStream_t stream) {
    const float* t_in    = (const float*)d_in[0];
    const float* xs      = (const float*)d_in[1];
    const float* h_init  = (const float*)d_in[2];
    const float* emb_w   = (const float*)d_in[3];
    const float* emb_b   = (const float*)d_in[4];
    const float* edge_w1 = (const float*)d_in[5];
    const float* edge_b1 = (const float*)d_in[6];
    const float* edge_w2 = (const float*)d_in[7];
    const float* edge_b2 = (const float*)d_in[8];
    const float* node_w1 = (const float*)d_in[9];
    const float* node_b1 = (const float*)d_in[10];
    const float* node_w2 = (const float*)d_in[11];
    const float* node_b2 = (const float*)d_in[12];
    const float* coord_w1= (const float*)d_in[13];
    const float* coord_b1= (const float*)d_in[14];
    const float* coord_w2= (const float*)d_in[15];
    float* out = (float*)d_out;

    const int B = in_sizes[0];                 // 1024
    const size_t w2t_bytes = (size_t)NLAYERS * HID * HID * sizeof(float);

    if (ws_size >= w2t_bytes) {
        float* w2t = (float*)d_ws;
        hipLaunchKernelGGL(w2_transpose_kernel, dim3(NLAYERS), dim3(BLOCK), 0,
                           stream, edge_w2, w2t);
        hipLaunchKernelGGL((egnn_fused_kernel<true>), dim3(B), dim3(BLOCK), 0,
                           stream, t_in, xs, h_init, emb_w, emb_b,
                           edge_w1, edge_b1, w2t, edge_b2,
                           node_w1, node_b1, node_w2, node_b2,
                           coord_w1, coord_b1, coord_w2, out);
    } else {
        hipLaunchKernelGGL((egnn_fused_kernel<false>), dim3(B), dim3(BLOCK), 0,
                           stream, t_in, xs, h_init, emb_w, emb_b,
                           edge_w1, edge_b1, edge_w2, edge_b2,
                           node_w1, node_b1, node_w2, node_b2,
                           coord_w1, coord_b1, coord_w2, out);
    }
}